// Round 1
// baseline (216.053 us; speedup 1.0000x reference)
//
#include <hip/hip_runtime.h>
#include <hip/hip_bf16.h>

// GroupLinear: out[t] = x[t] @ w[gid(t)].T
// T=8192, G=8, K=1024, N=2048; groups are contiguous token ranges (cumulative
// end-offsets in offs[], offs[G-1]==T).
//
// Strategy: convert x,w to bf16 in d_ws (2% abs tolerance permits bf16 MFMA),
// then m97-structure GEMM: 128x128 tile, BK=64, 4 waves (2x2), each wave 4x4
// of mfma_f32_16x16x32_bf16, global_load_lds width=16 staging.
// Group boundaries handled by per-fragment row masking (boundary tiles only).

#define T_DIM 8192
#define G_DIM 8
#define K_DIM 1024
#define N_DIM 2048

using short8 = __attribute__((ext_vector_type(8))) short;  // 8 x bf16 (4 VGPRs)
using f32x4  = __attribute__((ext_vector_type(4))) float;  // MFMA acc

typedef __attribute__((address_space(1))) void gvoid;  // global
typedef __attribute__((address_space(3))) void lvoid;  // LDS

// ---------------- fp32 -> bf16 convert (memory-bound, float4 in / 8B out) ---
__global__ __launch_bounds__(256) void cvt_kernel(const float* __restrict__ src,
                                                  ushort4* __restrict__ dst,
                                                  int n4) {
  int i = blockIdx.x * blockDim.x + threadIdx.x;
  if (i >= n4) return;
  float4 v = reinterpret_cast<const float4*>(src)[i];
  ushort4 o;
  o.x = __builtin_bit_cast(unsigned short, __float2bfloat16(v.x));
  o.y = __builtin_bit_cast(unsigned short, __float2bfloat16(v.y));
  o.z = __builtin_bit_cast(unsigned short, __float2bfloat16(v.z));
  o.w = __builtin_bit_cast(unsigned short, __float2bfloat16(v.w));
  dst[i] = o;
}

// ---------------- grouped bf16 GEMM ----------------------------------------
// One K-sweep of the 128x128 tile against expert weight block wg (N,K bf16,
// K contiguous — the natural B^T form for MFMA). MASKED: zero A-fragment rows
// outside [lo,hi) so boundary tiles can accumulate several experts.
template <bool MASKED>
__device__ __forceinline__ void tile_accum(const __hip_bfloat16* __restrict__ xb,
                                           const __hip_bfloat16* __restrict__ wg,
                                           __hip_bfloat16* As, __hip_bfloat16* Bs,
                                           f32x4 (&acc)[4][4],
                                           int m0, int n0, int lo, int hi) {
  const int lane = threadIdx.x & 63;
  const int wid  = threadIdx.x >> 6;
  const int wm   = wid >> 1;   // wave row  (0..1)
  const int wn   = wid & 1;    // wave col  (0..1)

  bool valid[4];
  if (MASKED) {
#pragma unroll
    for (int mt = 0; mt < 4; ++mt) {
      const int row = m0 + wm * 64 + mt * 16 + (lane & 15);
      valid[mt] = (row >= lo) && (row < hi);
    }
  }

  const int srow = lane >> 3;        // row within 8-row staging chunk
  const int scol = (lane & 7) * 8;   // bf16 element col within 64-wide K slab

  for (int kk = 0; kk < K_DIM / 64; ++kk) {
    const int k0 = kk * 64;
    // ---- stage A(128x64) and B(128x64) via global_load_lds width=16.
    // chunk j = 8 rows = 1024B; lane l -> LDS base + l*16B (wave-uniform base).
#pragma unroll
    for (int i = 0; i < 4; ++i) {
      const int j   = wid * 4 + i;        // 0..15
      const int row = j * 8 + srow;
      const __hip_bfloat16* ga = xb + (size_t)(m0 + row) * K_DIM + k0 + scol;
      const __hip_bfloat16* gb = wg + (size_t)(n0 + row) * K_DIM + k0 + scol;
      __builtin_amdgcn_global_load_lds((gvoid*)ga, (lvoid*)(As + j * 512), 16, 0, 0);
      __builtin_amdgcn_global_load_lds((gvoid*)gb, (lvoid*)(Bs + j * 512), 16, 0, 0);
    }
    __syncthreads();

    // ---- 2 k-steps of 32, 16 MFMAs each (per wave)
#pragma unroll
    for (int ks = 0; ks < 64; ks += 32) {
      const int ko = ks + (lane >> 4) * 8;
      short8 a[4], b[4];
      short8 z = {};
#pragma unroll
      for (int mt = 0; mt < 4; ++mt) {
        a[mt] = *reinterpret_cast<const short8*>(
            As + (wm * 64 + mt * 16 + (lane & 15)) * 64 + ko);
        if (MASKED) {
          if (!valid[mt]) a[mt] = z;   // per-lane select -> v_cndmask x4
        }
      }
#pragma unroll
      for (int nt = 0; nt < 4; ++nt) {
        b[nt] = *reinterpret_cast<const short8*>(
            Bs + (wn * 64 + nt * 16 + (lane & 15)) * 64 + ko);
      }
#pragma unroll
      for (int mt = 0; mt < 4; ++mt)
#pragma unroll
        for (int nt = 0; nt < 4; ++nt)
          acc[mt][nt] = __builtin_amdgcn_mfma_f32_16x16x32_bf16(
              a[mt], b[nt], acc[mt][nt], 0, 0, 0);
    }
    __syncthreads();
  }
}

__global__ __launch_bounds__(256) void grouped_gemm_kernel(
    const __hip_bfloat16* __restrict__ xb,
    const __hip_bfloat16* __restrict__ wb,
    const int* __restrict__ offs,
    float* __restrict__ out) {
  __shared__ __hip_bfloat16 As[128 * 64];  // 16 KiB, row-major [m][k]
  __shared__ __hip_bfloat16 Bs[128 * 64];  // 16 KiB, row-major [n][k]

  const int m0 = blockIdx.y * 128;
  const int n0 = blockIdx.x * 128;

  int offv[G_DIM];
#pragma unroll
  for (int g = 0; g < G_DIM; ++g) offv[g] = offs[g];

  // gid(t) = first g with offs[g] > t  (searchsorted side='right')
  int g_lo = 0;
  while (g_lo < G_DIM - 1 && offv[g_lo] <= m0) ++g_lo;
  int g_hi = g_lo;
  while (g_hi < G_DIM - 1 && offv[g_hi] <= m0 + 127) ++g_hi;

  f32x4 acc[4][4] = {};

  if (g_lo == g_hi) {
    // fast path: whole tile inside one group
    tile_accum<false>(xb, wb + (size_t)g_lo * N_DIM * K_DIM, As, Bs, acc,
                      m0, n0, 0, 0);
  } else {
    // boundary tile: accumulate each overlapping expert with row masking
    for (int g = g_lo; g <= g_hi; ++g) {
      const int lo = g ? offv[g - 1] : 0;
      const int hi = offv[g];
      if (hi <= lo) continue;  // empty group
      tile_accum<true>(xb, wb + (size_t)g * N_DIM * K_DIM, As, Bs, acc,
                       m0, n0, lo, hi);
    }
  }

  // epilogue: C/D layout col=lane&15, row=(lane>>4)*4+reg  [m89-verified]
  const int lane = threadIdx.x & 63;
  const int wid  = threadIdx.x >> 6;
  const int wm   = wid >> 1;
  const int wn   = wid & 1;
  const int quad = lane >> 4;
#pragma unroll
  for (int mt = 0; mt < 4; ++mt) {
#pragma unroll
    for (int nt = 0; nt < 4; ++nt) {
      const int row = m0 + wm * 64 + mt * 16 + quad * 4;
      const int col = n0 + wn * 64 + nt * 16 + (lane & 15);
#pragma unroll
      for (int r = 0; r < 4; ++r)
        out[(size_t)(row + r) * N_DIM + col] = acc[mt][nt][r];
    }
  }
}

// ---------------- fp32 fallback (only if d_ws < 48 MB; correctness-only) ----
__global__ __launch_bounds__(256) void fallback_kernel(
    const float* __restrict__ x, const float* __restrict__ w,
    const int* __restrict__ offs, float* __restrict__ out) {
  __shared__ float xs[K_DIM];
  const int t = blockIdx.y;
  int g = 0;
  while (g < G_DIM - 1 && offs[g] <= t) ++g;
  for (int i = threadIdx.x; i < K_DIM; i += blockDim.x)
    xs[i] = x[(size_t)t * K_DIM + i];
  __syncthreads();
  const int n = blockIdx.x * blockDim.x + threadIdx.x;
  const float* wr = w + ((size_t)g * N_DIM + n) * K_DIM;
  float s = 0.f;
  for (int k = 0; k < K_DIM; ++k) s += xs[k] * wr[k];
  out[(size_t)t * N_DIM + n] = s;
}

extern "C" void kernel_launch(void* const* d_in, const int* in_sizes, int n_in,
                              void* d_out, int out_size, void* d_ws, size_t ws_size,
                              hipStream_t stream) {
  const float* x    = (const float*)d_in[0];
  const float* w    = (const float*)d_in[1];
  const int*   offs = (const int*)d_in[2];
  float*       out  = (float*)d_out;

  const size_t x_elems = (size_t)T_DIM * K_DIM;            // 8.39M
  const size_t w_elems = (size_t)G_DIM * N_DIM * K_DIM;    // 16.78M
  const size_t need    = (x_elems + w_elems) * sizeof(__hip_bfloat16);  // 48 MiB

  if (ws_size < need) {
    fallback_kernel<<<dim3(N_DIM / 256, T_DIM), 256, 0, stream>>>(x, w, offs, out);
    return;
  }

  __hip_bfloat16* xb = (__hip_bfloat16*)d_ws;
  __hip_bfloat16* wb = xb + x_elems;

  const int n4x = (int)(x_elems / 4);  // 2,097,152 -> 8192 blocks
  const int n4w = (int)(w_elems / 4);  // 4,194,304 -> 16384 blocks
  cvt_kernel<<<n4x / 256, 256, 0, stream>>>(x, (ushort4*)xb, n4x);
  cvt_kernel<<<n4w / 256, 256, 0, stream>>>(w, (ushort4*)wb, n4w);

  grouped_gemm_kernel<<<dim3(N_DIM / 128, T_DIM / 128), 256, 0, stream>>>(
      xb, wb, offs, out);
}

// Round 2
// 191.254 us; speedup vs baseline: 1.1297x; 1.1297x over previous
//
#include <hip/hip_runtime.h>
#include <hip/hip_bf16.h>

// GroupLinear: out[t] = x[t] @ w[gid(t)].T
// T=8192, G=8, K=1024, N=2048; groups = contiguous token ranges (cum. end-offs).
//
// R2 changes vs R1 (82.6us GEMM, 1.4e7 LDS conflicts, 2x boundary stragglers):
//  1. grid.z = expert: boundary tiles get one uniform sweep per overlapping
//     expert (store-row masked) instead of a 2x-long masked block. No tail.
//  2. XOR-swizzled LDS layout: LDS[row][s] holds global 16B-block s^(row&7).
//     Staging global-src address is permuted (LDS dest must stay lane-
//     contiguous for global_load_lds); ds_read offset un-permutes. 16-way
//     bank conflict -> 8-quad degree-8 = b128 floor.
//  3. Converts fused into ONE kernel, 16B loads + 16B stores.

#define T_DIM 8192
#define G_DIM 8
#define K_DIM 1024
#define N_DIM 2048

using short8  = __attribute__((ext_vector_type(8))) short;   // 8 bf16
using f32x4   = __attribute__((ext_vector_type(4))) float;   // MFMA acc
using ushort8 = __attribute__((ext_vector_type(8))) unsigned short;

typedef __attribute__((address_space(1))) void gvoid;  // global
typedef __attribute__((address_space(3))) void lvoid;  // LDS

// ---------------- fused fp32 -> bf16 convert (16B in x2 / 16B out) ---------
__global__ __launch_bounds__(256) void cvt_kernel(const float* __restrict__ x,
                                                  const float* __restrict__ w,
                                                  ushort8* __restrict__ xb,
                                                  ushort8* __restrict__ wb,
                                                  int n8x, int n8tot) {
  int i = blockIdx.x * blockDim.x + threadIdx.x;
  if (i >= n8tot) return;
  const float4* s; ushort8* d; int j;
  if (i < n8x) { s = (const float4*)x; d = xb; j = i; }
  else         { s = (const float4*)w; d = wb; j = i - n8x; }
  float4 v0 = s[2 * j], v1 = s[2 * j + 1];
  ushort8 o;
  o[0] = __builtin_bit_cast(unsigned short, __float2bfloat16(v0.x));
  o[1] = __builtin_bit_cast(unsigned short, __float2bfloat16(v0.y));
  o[2] = __builtin_bit_cast(unsigned short, __float2bfloat16(v0.z));
  o[3] = __builtin_bit_cast(unsigned short, __float2bfloat16(v0.w));
  o[4] = __builtin_bit_cast(unsigned short, __float2bfloat16(v1.x));
  o[5] = __builtin_bit_cast(unsigned short, __float2bfloat16(v1.y));
  o[6] = __builtin_bit_cast(unsigned short, __float2bfloat16(v1.z));
  o[7] = __builtin_bit_cast(unsigned short, __float2bfloat16(v1.w));
  d[j] = o;
}

// ---------------- grouped bf16 GEMM, one expert per blockIdx.z -------------
__global__ __launch_bounds__(256) void grouped_gemm_kernel(
    const __hip_bfloat16* __restrict__ xb,
    const __hip_bfloat16* __restrict__ wb,
    const int* __restrict__ offs,
    float* __restrict__ out) {
  const int g  = blockIdx.z;
  const int m0 = blockIdx.y * 128;
  const int n0 = blockIdx.x * 128;
  const int lo = g ? offs[g - 1] : 0;
  const int hi = offs[g];
  // block-uniform early exit: expert g doesn't own any row of this M-tile
  if (lo >= m0 + 128 || hi <= m0 || hi <= lo) return;

  __shared__ __align__(16) __hip_bfloat16 As[128 * 64];  // [m][k], swizzled
  __shared__ __align__(16) __hip_bfloat16 Bs[128 * 64];  // [n][k], swizzled

  const __hip_bfloat16* wg = wb + (size_t)g * N_DIM * K_DIM;

  const int lane = threadIdx.x & 63;
  const int wid  = threadIdx.x >> 6;
  const int wm   = wid >> 1;   // wave row (0..1)
  const int wn   = wid & 1;    // wave col (0..1)

  // staging: chunk j = 8 rows x 64 cols = 1KB; lane l -> LDS base + l*16B.
  // row&7 == srow, so the XOR swizzle permutes the GLOBAL column block.
  const int srow = lane >> 3;                  // row within chunk
  const int scol = ((lane & 7) ^ srow) * 8;    // swizzled global col (elems)

  f32x4 acc[4][4] = {};

  for (int kk = 0; kk < K_DIM / 64; ++kk) {
    const int k0 = kk * 64;
#pragma unroll
    for (int i = 0; i < 4; ++i) {
      const int j   = wid * 4 + i;      // 0..15
      const int row = j * 8 + srow;
      const __hip_bfloat16* ga = xb + (size_t)(m0 + row) * K_DIM + k0 + scol;
      const __hip_bfloat16* gb = wg + (size_t)(n0 + row) * K_DIM + k0 + scol;
      __builtin_amdgcn_global_load_lds((gvoid*)ga, (lvoid*)(As + j * 512), 16, 0, 0);
      __builtin_amdgcn_global_load_lds((gvoid*)gb, (lvoid*)(Bs + j * 512), 16, 0, 0);
    }
    __syncthreads();

#pragma unroll
    for (int ks = 0; ks < 2; ++ks) {
      // global 16B-block index this lane needs: kb = ks*4 + (lane>>4)
      // fragment rows have row&7 == lane&7 -> swizzled offset:
      const int kb  = ks * 4 + (lane >> 4);
      const int off = ((kb ^ (lane & 7)) * 8);
      short8 a[4], b[4];
#pragma unroll
      for (int mt = 0; mt < 4; ++mt)
        a[mt] = *reinterpret_cast<const short8*>(
            As + (wm * 64 + mt * 16 + (lane & 15)) * 64 + off);
#pragma unroll
      for (int nt = 0; nt < 4; ++nt)
        b[nt] = *reinterpret_cast<const short8*>(
            Bs + (wn * 64 + nt * 16 + (lane & 15)) * 64 + off);
#pragma unroll
      for (int mt = 0; mt < 4; ++mt)
#pragma unroll
        for (int nt = 0; nt < 4; ++nt)
          acc[mt][nt] = __builtin_amdgcn_mfma_f32_16x16x32_bf16(
              a[mt], b[nt], acc[mt][nt], 0, 0, 0);
    }
    __syncthreads();
  }

  // epilogue: C/D layout col=lane&15, row=(lane>>4)*4+reg  [m89-verified]
  // store ONLY rows this expert owns ([lo,hi)) — boundary tiles are written
  // by one block per overlapping expert, disjoint rows.
  const int quad = lane >> 4;
#pragma unroll
  for (int mt = 0; mt < 4; ++mt) {
    const int rbase = m0 + wm * 64 + mt * 16 + quad * 4;
#pragma unroll
    for (int r = 0; r < 4; ++r) {
      const int row = rbase + r;
      if (row < lo || row >= hi) continue;
#pragma unroll
      for (int nt = 0; nt < 4; ++nt) {
        const int col = n0 + wn * 64 + nt * 16 + (lane & 15);
        out[(size_t)row * N_DIM + col] = acc[mt][nt][r];
      }
    }
  }
}

// ---------------- fp32 fallback (only if d_ws < 48 MB; correctness-only) ----
__global__ __launch_bounds__(256) void fallback_kernel(
    const float* __restrict__ x, const float* __restrict__ w,
    const int* __restrict__ offs, float* __restrict__ out) {
  __shared__ float xs[K_DIM];
  const int t = blockIdx.y;
  int g = 0;
  while (g < G_DIM - 1 && offs[g] <= t) ++g;
  for (int i = threadIdx.x; i < K_DIM; i += blockDim.x)
    xs[i] = x[(size_t)t * K_DIM + i];
  __syncthreads();
  const int n = blockIdx.x * blockDim.x + threadIdx.x;
  const float* wr = w + ((size_t)g * N_DIM + n) * K_DIM;
  float s = 0.f;
  for (int k = 0; k < K_DIM; ++k) s += xs[k] * wr[k];
  out[(size_t)t * N_DIM + n] = s;
}

extern "C" void kernel_launch(void* const* d_in, const int* in_sizes, int n_in,
                              void* d_out, int out_size, void* d_ws, size_t ws_size,
                              hipStream_t stream) {
  const float* x    = (const float*)d_in[0];
  const float* w    = (const float*)d_in[1];
  const int*   offs = (const int*)d_in[2];
  float*       out  = (float*)d_out;

  const size_t x_elems = (size_t)T_DIM * K_DIM;            // 8.39M
  const size_t w_elems = (size_t)G_DIM * N_DIM * K_DIM;    // 16.78M
  const size_t need    = (x_elems + w_elems) * sizeof(__hip_bfloat16);  // 48 MiB

  if (ws_size < need) {
    fallback_kernel<<<dim3(N_DIM / 256, T_DIM), 256, 0, stream>>>(x, w, offs, out);
    return;
  }

  __hip_bfloat16* xb = (__hip_bfloat16*)d_ws;
  __hip_bfloat16* wb = xb + x_elems;

  const int n8x   = (int)(x_elems / 8);            // 1,048,576
  const int n8tot = (int)((x_elems + w_elems) / 8);  // 3,145,728
  cvt_kernel<<<(n8tot + 255) / 256, 256, 0, stream>>>(
      x, w, (ushort8*)xb, (ushort8*)wb, n8x, n8tot);

  grouped_gemm_kernel<<<dim3(N_DIM / 128, T_DIM / 128, G_DIM), 256, 0, stream>>>(
      xb, wb, offs, out);
}